// Round 11
// baseline (220.952 us; speedup 1.0000x reference)
//
#include <hip/hip_runtime.h>
#include <hip/hip_bf16.h>

#define BATCH 8
#define NN    2048
#define DD    64
#define BN    (BATCH * NN)          // 16384 rows
#define MWORDS 68                   // padded words per mask row in LDS

typedef __attribute__((ext_vector_type(8))) short bf16x8;
typedef __attribute__((ext_vector_type(4))) float f32x4;

// pack two fp32 into one dword of two RNE-rounded bf16 (lo, hi)
static __device__ __forceinline__ unsigned f2bf_pk(float lo, float hi) {
  unsigned ul = __float_as_uint(lo);
  unsigned uh = __float_as_uint(hi);
  ul = (ul + 0x7fffu + ((ul >> 16) & 1u)) >> 16;
  uh = (uh + 0x7fffu + ((uh >> 16) & 1u)) & 0xffff0000u;
  return ul | uh;
}

// -------------------------------------------------------------------------
// Kernel A (dual role):
//  blocks 0..511    : k1 = relu(h@W), t1, t2, frag-native bf16 hwT
//  blocks 512..4607 : kpack = adj -> bitmasks (row-major coalesced, root-skip)
// Fusing overlaps kpack's HBM stream with k1's latency-bound compute.
// -------------------------------------------------------------------------
__global__ __launch_bounds__(256) void kA(
    const float* __restrict__ h, const float* __restrict__ W,
    const float* __restrict__ a1, const float* __restrict__ a2,
    const int* __restrict__ adj, const float* __restrict__ h_root,
    unsigned short* __restrict__ hwT, float* __restrict__ t1,
    float* __restrict__ t2, unsigned* __restrict__ masks) {
  if (blockIdx.x >= 512) {
    // ---- kpack role: 4096 blocks, 4 waves = 4 rows ----
    const int row  = (blockIdx.x - 512) * 4 + (threadIdx.x >> 6);
    const int lane = threadIdx.x & 63;
    if (h_root[row] <= 0.f) return;        // wave-uniform skip
    const int* ap = adj + (size_t)row * NN + lane * 32;
    unsigned word = 0;
#pragma unroll
    for (int i = 0; i < 8; ++i) {
      int4 v = *reinterpret_cast<const int4*>(ap + i * 4);
      word |= (v.x > 0 ? 1u : 0u) << (i * 4 + 0);
      word |= (v.y > 0 ? 1u : 0u) << (i * 4 + 1);
      word |= (v.z > 0 ? 1u : 0u) << (i * 4 + 2);
      word |= (v.w > 0 ? 1u : 0u) << (i * 4 + 3);
    }
    masks[(size_t)row * 64 + lane] = word;
    return;
  }

  // ---- k1 role: 512 blocks, 32 rows each ----
  __shared__ float ht[64 * 36];
  __shared__ float Ws[64 * 64];
  __shared__ unsigned short bt[64 * 40];

  const int t  = threadIdx.x;
  const int r0 = blockIdx.x * 32;

#pragma unroll
  for (int r = 0; r < 4; ++r) {
    int f = t + 256 * r;
    reinterpret_cast<float4*>(Ws)[f] = reinterpret_cast<const float4*>(W)[f];
  }
#pragma unroll
  for (int r = 0; r < 2; ++r) {
    int f = t + 256 * r;
    int i = f >> 4, j4 = f & 15;
    float4 v = reinterpret_cast<const float4*>(h + (size_t)(r0 + i) * DD)[j4];
    ht[(4 * j4 + 0) * 36 + i] = v.x;
    ht[(4 * j4 + 1) * 36 + i] = v.y;
    ht[(4 * j4 + 2) * 36 + i] = v.z;
    ht[(4 * j4 + 3) * 36 + i] = v.w;
  }
  __syncthreads();

  const int trow = t >> 4, kcol = t & 15;
  float4 acc0 = make_float4(0.f, 0.f, 0.f, 0.f);
  float4 acc1 = make_float4(0.f, 0.f, 0.f, 0.f);

#pragma unroll 8
  for (int j = 0; j < 64; ++j) {
    float2 hv = *reinterpret_cast<const float2*>(&ht[j * 36 + 2 * trow]);
    float4 wv = reinterpret_cast<const float4*>(Ws)[j * 16 + kcol];
    acc0.x = fmaf(hv.x, wv.x, acc0.x); acc0.y = fmaf(hv.x, wv.y, acc0.y);
    acc0.z = fmaf(hv.x, wv.z, acc0.z); acc0.w = fmaf(hv.x, wv.w, acc0.w);
    acc1.x = fmaf(hv.y, wv.x, acc1.x); acc1.y = fmaf(hv.y, wv.y, acc1.y);
    acc1.z = fmaf(hv.y, wv.z, acc1.z); acc1.w = fmaf(hv.y, wv.w, acc1.w);
  }

  acc0.x = fmaxf(acc0.x, 0.f); acc0.y = fmaxf(acc0.y, 0.f);
  acc0.z = fmaxf(acc0.z, 0.f); acc0.w = fmaxf(acc0.w, 0.f);
  acc1.x = fmaxf(acc1.x, 0.f); acc1.y = fmaxf(acc1.y, 0.f);
  acc1.z = fmaxf(acc1.z, 0.f); acc1.w = fmaxf(acc1.w, 0.f);

  float4 a1v = reinterpret_cast<const float4*>(a1)[kcol];
  float4 a2v = reinterpret_cast<const float4*>(a2)[kcol];
  float s1_0 = acc0.x * a1v.x + acc0.y * a1v.y + acc0.z * a1v.z + acc0.w * a1v.w;
  float s1_1 = acc1.x * a1v.x + acc1.y * a1v.y + acc1.z * a1v.z + acc1.w * a1v.w;
  float s2_0 = acc0.x * a2v.x + acc0.y * a2v.y + acc0.z * a2v.z + acc0.w * a2v.w;
  float s2_1 = acc1.x * a2v.x + acc1.y * a2v.y + acc1.z * a2v.z + acc1.w * a2v.w;
#pragma unroll
  for (int mm = 1; mm <= 8; mm <<= 1) {
    s1_0 += __shfl_xor(s1_0, mm, 64);
    s1_1 += __shfl_xor(s1_1, mm, 64);
    s2_0 += __shfl_xor(s2_0, mm, 64);
    s2_1 += __shfl_xor(s2_1, mm, 64);
  }
  {
    int row = r0 + 2 * trow;
    if (kcol == 0) {
      t1[row] = s1_0; t1[row + 1] = s1_1;
      t2[row] = s2_0; t2[row + 1] = s2_1;
    }
  }

  {
    const float* a0 = &acc0.x;
    const float* a1p = &acc1.x;
#pragma unroll
    for (int c = 0; c < 4; ++c) {
      int k = 4 * kcol + c;
      *reinterpret_cast<unsigned*>(&bt[k * 40 + 2 * trow]) = f2bf_pk(a0[c], a1p[c]);
    }
  }
  __syncthreads();
  {
    int k = t >> 2, jp = t & 3;
    int g = k >> 4, n = k & 15;
    int bb = r0 >> 11;
    int jb = r0 & (NN - 1);
    int ks = jb >> 5;
    size_t base = ((((size_t)bb * (NN / 32) + ks) * 4 + g) * 64 + (jp * 16 + n)) * 8;
    *reinterpret_cast<int4*>(hwT + base) = *reinterpret_cast<const int4*>(&bt[k * 40 + jp * 8]);
  }
}

// -------------------------------------------------------------------------
// Kernel 2a: P-generation. Pure VALU + coalesced stream (no MFMA).
// For each (b, 16-row i-tile, kstep): build bf16 A-fragment from mask bits,
// t1, t2 (p = bit ? exp(relu(t1+t2)) : 1) and write it frag-native to ws:
//   pfrag[(((bid*64)+ks)*64 + lane)*8]  (1 KB contiguous per wave-kstep).
// Also reduces den[row] (full j-sum per row). Floor: 67 MB write ~ 11 us.
// grid = B*128 = 1024 blocks, 256 threads; wave w owns ks = w*16..w*16+15.
// -------------------------------------------------------------------------
__global__ __launch_bounds__(256, 4) void k2a_pgen(
    const unsigned* __restrict__ masks, const float* __restrict__ t1,
    const float* __restrict__ t2,
    unsigned short* __restrict__ pfrag, float* __restrict__ den) {
  __shared__ unsigned maskS[16 * MWORDS];   // 4.3 KB
  __shared__ float t2s[NN];                 // 8 KB
  __shared__ float t1s[16];
  __shared__ float denP[4][16];

  const int t    = threadIdx.x;
  const int bid  = blockIdx.x;               // b*128 + it
  const int b    = bid >> 7;
  const int i0   = (bid & 127) * 16;
  const int w    = t >> 6;
  const int lane = t & 63;
  const int m    = lane & 15;
  const int quad = lane >> 4;
  const int rowbase = b * NN + i0;

#pragma unroll
  for (int r = 0; r < 2; ++r)
    reinterpret_cast<float4*>(t2s)[t + 256 * r] =
        reinterpret_cast<const float4*>(t2 + b * NN)[t + 256 * r];
  {
    int row = t >> 4, w4 = t & 15;
    int4 mv = *reinterpret_cast<const int4*>(
        masks + (size_t)(rowbase + row) * 64 + w4 * 4);
    *reinterpret_cast<int4*>(&maskS[row * MWORDS + w4 * 4]) = mv;
  }
  if (t < 16) t1s[t] = t1[rowbase + t];
  __syncthreads();

  const float t1v = t1s[m];
  const int ks0 = w * 16;
  float den_acc = 0.f;
  unsigned short* pout = pfrag + (((size_t)bid * 64 + ks0) * 64 + lane) * 8;

#pragma unroll 1
  for (int kk = 0; kk < 16; ++kk) {
    const int ks = ks0 + kk;
    const unsigned mw  = maskS[m * MWORDS + ks];
    const unsigned mm8 = mw >> (quad * 8);
    const float* t2p = &t2s[ks * 32 + quad * 8];
    float4 e0 = *reinterpret_cast<const float4*>(t2p);
    float4 e1 = *reinterpret_cast<const float4*>(t2p + 4);

    float p0 = (mm8 & 1u)   ? __expf(fmaxf(t1v + e0.x, 0.f)) : 1.f;
    float p1 = (mm8 & 2u)   ? __expf(fmaxf(t1v + e0.y, 0.f)) : 1.f;
    float p2 = (mm8 & 4u)   ? __expf(fmaxf(t1v + e0.z, 0.f)) : 1.f;
    float p3 = (mm8 & 8u)   ? __expf(fmaxf(t1v + e0.w, 0.f)) : 1.f;
    float p4 = (mm8 & 16u)  ? __expf(fmaxf(t1v + e1.x, 0.f)) : 1.f;
    float p5 = (mm8 & 32u)  ? __expf(fmaxf(t1v + e1.y, 0.f)) : 1.f;
    float p6 = (mm8 & 64u)  ? __expf(fmaxf(t1v + e1.z, 0.f)) : 1.f;
    float p7 = (mm8 & 128u) ? __expf(fmaxf(t1v + e1.w, 0.f)) : 1.f;
    den_acc += ((p0 + p1) + (p2 + p3)) + ((p4 + p5) + (p6 + p7));

    int4 Af;
    Af.x = (int)f2bf_pk(p0, p1);
    Af.y = (int)f2bf_pk(p2, p3);
    Af.z = (int)f2bf_pk(p4, p5);
    Af.w = (int)f2bf_pk(p6, p7);
    *reinterpret_cast<int4*>(pout + (size_t)kk * 512) = Af;
  }

  // den: reduce quads in-wave, then the 4 waves via LDS
  den_acc += __shfl_xor(den_acc, 16, 64);
  den_acc += __shfl_xor(den_acc, 32, 64);
  if (quad == 0) denP[w][m] = den_acc;
  __syncthreads();
  if (t < 16)
    den[rowbase + t] = (denP[0][t] + denP[1][t]) + (denP[2][t] + denP[3][t]);
}

// -------------------------------------------------------------------------
// Kernel 2b: pure MFMA GEMM (m97-style instruction mix).
// Per kstep: 1 A-frag load (frag-native pfrag, L3-resident stream) +
// 4 B-frag loads (frag-native hwT, L2-resident) + 4 MFMA. Epilogue:
// 4-wave LDS reduce + den normalize + root-select + store out.
// grid = B*128 = 1024 blocks, 256 threads; wave w owns ks = w*16..w*16+15.
// -------------------------------------------------------------------------
__global__ __launch_bounds__(256, 4) void k2b_gemm(
    const unsigned short* __restrict__ hwT, const unsigned short* __restrict__ pfrag,
    const float* __restrict__ den, const float* __restrict__ h,
    const float* __restrict__ h_root, float* __restrict__ out) {
  __shared__ float os[4][16][68];           // 17.4 KB

  const int t    = threadIdx.x;
  const int bid  = blockIdx.x;               // b*128 + it
  const int b    = bid >> 7;
  const int i0   = (bid & 127) * 16;
  const int w    = t >> 6;
  const int lane = t & 63;
  const int m    = lane & 15;
  const int quad = lane >> 4;
  const int rowbase = b * NN + i0;

  f32x4 acc[4];
#pragma unroll
  for (int g = 0; g < 4; ++g) acc[g] = (f32x4){0.f, 0.f, 0.f, 0.f};

  const int ks0 = w * 16;
  const unsigned short* pin = pfrag + (((size_t)bid * 64 + ks0) * 64 + lane) * 8;
  const unsigned short* bbase =
      hwT + ((((size_t)b * (NN / 32) + ks0) * 4) * 64 + lane) * 8;

#pragma unroll 1
  for (int kk = 0; kk < 16; ++kk) {
    bf16x8 A = *reinterpret_cast<const bf16x8*>(pin + (size_t)kk * 512);
    const unsigned short* bp = bbase + (size_t)kk * 2048;  // 4*64*8 shorts per ks
    bf16x8 B0 = *reinterpret_cast<const bf16x8*>(bp);
    bf16x8 B1 = *reinterpret_cast<const bf16x8*>(bp + 512);
    bf16x8 B2 = *reinterpret_cast<const bf16x8*>(bp + 1024);
    bf16x8 B3 = *reinterpret_cast<const bf16x8*>(bp + 1536);

    acc[0] = __builtin_amdgcn_mfma_f32_16x16x32_bf16(A, B0, acc[0], 0, 0, 0);
    acc[1] = __builtin_amdgcn_mfma_f32_16x16x32_bf16(A, B1, acc[1], 0, 0, 0);
    acc[2] = __builtin_amdgcn_mfma_f32_16x16x32_bf16(A, B2, acc[2], 0, 0, 0);
    acc[3] = __builtin_amdgcn_mfma_f32_16x16x32_bf16(A, B3, acc[3], 0, 0, 0);
  }

  // per-wave partial C(16x64) into LDS
#pragma unroll
  for (int g = 0; g < 4; ++g)
#pragma unroll
    for (int r = 0; r < 4; ++r)
      os[w][quad * 4 + r][g * 16 + m] = acc[g][r];
  __syncthreads();

  // block reduce over the 4 waves + normalize + root-select + store
  {
    const int i = t >> 4, k4 = t & 15;
    float4 a = make_float4(0.f, 0.f, 0.f, 0.f);
#pragma unroll
    for (int ww = 0; ww < 4; ++ww) {
      float4 p = *reinterpret_cast<const float4*>(&os[ww][i][k4 * 4]);
      a.x += p.x; a.y += p.y; a.z += p.z; a.w += p.w;
    }
    const size_t row = (size_t)rowbase + i;
    float4 res;
    if (h_root[row] > 0.f) {
      const float inv = 1.f / den[row];
      res.x = a.x * inv; res.y = a.y * inv; res.z = a.z * inv; res.w = a.w * inv;
    } else {
      res = reinterpret_cast<const float4*>(h + row * DD)[k4];
    }
    reinterpret_cast<float4*>(out + row * DD)[k4] = res;
  }
}

extern "C" void kernel_launch(void* const* d_in, const int* in_sizes, int n_in,
                              void* d_out, int out_size, void* d_ws, size_t ws_size,
                              hipStream_t stream) {
  const float* h      = (const float*)d_in[0];
  const int*   adj    = (const int*)d_in[1];
  const float* h_root = (const float*)d_in[2];
  const float* W      = (const float*)d_in[3];
  const float* a1     = (const float*)d_in[4];
  const float* a2     = (const float*)d_in[5];
  float* out = (float*)d_out;

  // ws: hwT (bf16 BN*DD) | t1 | t2 | den | masks (BN*64 u32) | pfrag (bf16 BN*NN)
  unsigned short* hwT = (unsigned short*)d_ws;
  float* t1 = (float*)(hwT + (size_t)BN * DD);
  float* t2 = t1 + BN;
  float* den = t2 + BN;
  unsigned* masks = (unsigned*)(den + BN);
  unsigned short* pfrag = (unsigned short*)(masks + (size_t)BN * 64);

  kA<<<512 + BN / 4, 256, 0, stream>>>(h, W, a1, a2, adj, h_root, hwT, t1, t2, masks);
  k2a_pgen<<<BATCH * 128, 256, 0, stream>>>(masks, t1, t2, pfrag, den);
  k2b_gemm<<<BATCH * 128, 256, 0, stream>>>(hwT, pfrag, den, h, h_root, out);
}

// Round 12
// 207.175 us; speedup vs baseline: 1.0665x; 1.0665x over previous
//
#include <hip/hip_runtime.h>
#include <hip/hip_bf16.h>

#define BATCH 8
#define NN    2048
#define DD    64
#define BN    (BATCH * NN)          // 16384 rows
#define MWORDS 68                   // padded words per mask row in LDS

typedef __attribute__((ext_vector_type(8))) short bf16x8;
typedef __attribute__((ext_vector_type(4))) float f32x4;

// pack two fp32 into one dword of two RNE-rounded bf16 (lo, hi)
static __device__ __forceinline__ unsigned f2bf_pk(float lo, float hi) {
  unsigned ul = __float_as_uint(lo);
  unsigned uh = __float_as_uint(hi);
  ul = (ul + 0x7fffu + ((ul >> 16) & 1u)) >> 16;
  uh = (uh + 0x7fffu + ((uh >> 16) & 1u)) & 0xffff0000u;
  return ul | uh;
}

// -------------------------------------------------------------------------
// Kernel A (dual role):
//  blocks 0..511    : k1 = relu(h@W), t1, t2, frag-native bf16 hwT
//  blocks 512..4607 : kpack = adj -> bitmasks (row-major coalesced, root-skip)
// -------------------------------------------------------------------------
__global__ __launch_bounds__(256) void kA(
    const float* __restrict__ h, const float* __restrict__ W,
    const float* __restrict__ a1, const float* __restrict__ a2,
    const int* __restrict__ adj, const float* __restrict__ h_root,
    unsigned short* __restrict__ hwT, float* __restrict__ t1,
    float* __restrict__ t2, unsigned* __restrict__ masks) {
  if (blockIdx.x >= 512) {
    const int row  = (blockIdx.x - 512) * 4 + (threadIdx.x >> 6);
    const int lane = threadIdx.x & 63;
    if (h_root[row] <= 0.f) return;        // wave-uniform skip
    const int* ap = adj + (size_t)row * NN + lane * 32;
    unsigned word = 0;
#pragma unroll
    for (int i = 0; i < 8; ++i) {
      int4 v = *reinterpret_cast<const int4*>(ap + i * 4);
      word |= (v.x > 0 ? 1u : 0u) << (i * 4 + 0);
      word |= (v.y > 0 ? 1u : 0u) << (i * 4 + 1);
      word |= (v.z > 0 ? 1u : 0u) << (i * 4 + 2);
      word |= (v.w > 0 ? 1u : 0u) << (i * 4 + 3);
    }
    masks[(size_t)row * 64 + lane] = word;
    return;
  }

  // ---- k1 role: 512 blocks, 32 rows each ----
  __shared__ float ht[64 * 36];
  __shared__ float Ws[64 * 64];
  __shared__ unsigned short bt[64 * 40];

  const int t  = threadIdx.x;
  const int r0 = blockIdx.x * 32;

#pragma unroll
  for (int r = 0; r < 4; ++r) {
    int f = t + 256 * r;
    reinterpret_cast<float4*>(Ws)[f] = reinterpret_cast<const float4*>(W)[f];
  }
#pragma unroll
  for (int r = 0; r < 2; ++r) {
    int f = t + 256 * r;
    int i = f >> 4, j4 = f & 15;
    float4 v = reinterpret_cast<const float4*>(h + (size_t)(r0 + i) * DD)[j4];
    ht[(4 * j4 + 0) * 36 + i] = v.x;
    ht[(4 * j4 + 1) * 36 + i] = v.y;
    ht[(4 * j4 + 2) * 36 + i] = v.z;
    ht[(4 * j4 + 3) * 36 + i] = v.w;
  }
  __syncthreads();

  const int trow = t >> 4, kcol = t & 15;
  float4 acc0 = make_float4(0.f, 0.f, 0.f, 0.f);
  float4 acc1 = make_float4(0.f, 0.f, 0.f, 0.f);

#pragma unroll 8
  for (int j = 0; j < 64; ++j) {
    float2 hv = *reinterpret_cast<const float2*>(&ht[j * 36 + 2 * trow]);
    float4 wv = reinterpret_cast<const float4*>(Ws)[j * 16 + kcol];
    acc0.x = fmaf(hv.x, wv.x, acc0.x); acc0.y = fmaf(hv.x, wv.y, acc0.y);
    acc0.z = fmaf(hv.x, wv.z, acc0.z); acc0.w = fmaf(hv.x, wv.w, acc0.w);
    acc1.x = fmaf(hv.y, wv.x, acc1.x); acc1.y = fmaf(hv.y, wv.y, acc1.y);
    acc1.z = fmaf(hv.y, wv.z, acc1.z); acc1.w = fmaf(hv.y, wv.w, acc1.w);
  }

  acc0.x = fmaxf(acc0.x, 0.f); acc0.y = fmaxf(acc0.y, 0.f);
  acc0.z = fmaxf(acc0.z, 0.f); acc0.w = fmaxf(acc0.w, 0.f);
  acc1.x = fmaxf(acc1.x, 0.f); acc1.y = fmaxf(acc1.y, 0.f);
  acc1.z = fmaxf(acc1.z, 0.f); acc1.w = fmaxf(acc1.w, 0.f);

  float4 a1v = reinterpret_cast<const float4*>(a1)[kcol];
  float4 a2v = reinterpret_cast<const float4*>(a2)[kcol];
  float s1_0 = acc0.x * a1v.x + acc0.y * a1v.y + acc0.z * a1v.z + acc0.w * a1v.w;
  float s1_1 = acc1.x * a1v.x + acc1.y * a1v.y + acc1.z * a1v.z + acc1.w * a1v.w;
  float s2_0 = acc0.x * a2v.x + acc0.y * a2v.y + acc0.z * a2v.z + acc0.w * a2v.w;
  float s2_1 = acc1.x * a2v.x + acc1.y * a2v.y + acc1.z * a2v.z + acc1.w * a2v.w;
#pragma unroll
  for (int mm = 1; mm <= 8; mm <<= 1) {
    s1_0 += __shfl_xor(s1_0, mm, 64);
    s1_1 += __shfl_xor(s1_1, mm, 64);
    s2_0 += __shfl_xor(s2_0, mm, 64);
    s2_1 += __shfl_xor(s2_1, mm, 64);
  }
  {
    int row = r0 + 2 * trow;
    if (kcol == 0) {
      t1[row] = s1_0; t1[row + 1] = s1_1;
      t2[row] = s2_0; t2[row + 1] = s2_1;
    }
  }

  {
    const float* a0 = &acc0.x;
    const float* a1p = &acc1.x;
#pragma unroll
    for (int c = 0; c < 4; ++c) {
      int k = 4 * kcol + c;
      *reinterpret_cast<unsigned*>(&bt[k * 40 + 2 * trow]) = f2bf_pk(a0[c], a1p[c]);
    }
  }
  __syncthreads();
  {
    int k = t >> 2, jp = t & 3;
    int g = k >> 4, n = k & 15;
    int bb = r0 >> 11;
    int jb = r0 & (NN - 1);
    int ks = jb >> 5;
    size_t base = ((((size_t)bb * (NN / 32) + ks) * 4 + g) * 64 + (jp * 16 + n)) * 8;
    *reinterpret_cast<int4*>(hwT + base) = *reinterpret_cast<const int4*>(&bt[k * 40 + jp * 8]);
  }
}

// -------------------------------------------------------------------------
// Kernel 2: fused MFMA attention, XCD-AWARE SWIZZLE: b = blockIdx & 7, so
// all 128 blocks of a batch land on ONE XCD (round-robin dispatch) and the
// batch's hwT slice (2 MB) + masks (0.5 MB) stay resident in that XCD's
// 4 MB L2 — B-frags now L2-hit instead of thrashing through L3.
// maskS staged coalesced; B-frags lane-contiguous from frag-native hwT;
// A-frag (P) built in regs from mask bits + exp; 4 waves partition j;
// LDS-reduce epilogue writes out directly. Inactive rows (poison masks)
// compute bounded garbage, discarded by root-select.
// grid = 1024 blocks (4/CU), 256 threads.
// -------------------------------------------------------------------------
__global__ __launch_bounds__(256, 4) void k2_attn(
    const unsigned short* __restrict__ hwT, const unsigned* __restrict__ masks,
    const float* __restrict__ t1, const float* __restrict__ t2,
    const float* __restrict__ h, const float* __restrict__ h_root,
    float* __restrict__ out) {
  __shared__ unsigned maskS[16 * MWORDS];   // 4.3 KB
  __shared__ float t2s[NN];                 // 8 KB
  __shared__ float os[4][16][68];           // 17.4 KB
  __shared__ float denos[4][16];

  const int t    = threadIdx.x;
  const int b    = blockIdx.x & 7;           // XCD-aware: batch == XCD
  const int i0   = (blockIdx.x >> 3) * 16;   // block's 16-row tile
  const int w    = t >> 6;                   // wave id = j quarter
  const int lane = t & 63;
  const int m    = lane & 15;
  const int quad = lane >> 4;
  const int rowbase = b * NN + i0;

  // stage t2 row-block (coalesced)
#pragma unroll
  for (int r = 0; r < 2; ++r)
    reinterpret_cast<float4*>(t2s)[t + 256 * r] =
        reinterpret_cast<const float4*>(t2 + b * NN)[t + 256 * r];

  // stage masks: 16 rows x 64 words = 4 KB contiguous, one int4/thread
  {
    int row = t >> 4, w4 = t & 15;
    int4 mv = *reinterpret_cast<const int4*>(
        masks + ((size_t)(rowbase + row)) * 64 + w4 * 4);
    *reinterpret_cast<int4*>(&maskS[row * MWORDS + w4 * 4]) = mv;
  }
  __syncthreads();

  // compute: wave w owns ks = w*16 .. w*16+15 (512 j)
  const float t1v = t1[rowbase + m];
  const int ks0 = w * 16;

  f32x4 acc[4];
#pragma unroll
  for (int g = 0; g < 4; ++g) acc[g] = (f32x4){0.f, 0.f, 0.f, 0.f};
  float den = 0.f;

  unsigned mcur = maskS[m * MWORDS + ks0];

#pragma unroll 1
  for (int kk = 0; kk < 16; ++kk) {
    const int ks = ks0 + kk;
    unsigned mnext = 0;
    if (kk + 1 < 16) mnext = maskS[m * MWORDS + ks + 1];

    // B-frags: lane-contiguous 1 KB per load (XCD-local L2-resident hwT)
    const unsigned short* bp =
        hwT + ((((size_t)b * (NN / 32) + ks) * 4) * 64 + lane) * 8;
    bf16x8 B0 = *reinterpret_cast<const bf16x8*>(bp);
    bf16x8 B1 = *reinterpret_cast<const bf16x8*>(bp + 512);
    bf16x8 B2 = *reinterpret_cast<const bf16x8*>(bp + 1024);
    bf16x8 B3 = *reinterpret_cast<const bf16x8*>(bp + 1536);

    const float* t2p = &t2s[ks * 32 + quad * 8];
    float4 e0 = *reinterpret_cast<const float4*>(t2p);
    float4 e1 = *reinterpret_cast<const float4*>(t2p + 4);

    const unsigned mm8 = mcur >> (quad * 8);
    float p0 = (mm8 & 1u)   ? __expf(fmaxf(t1v + e0.x, 0.f)) : 1.f;
    float p1 = (mm8 & 2u)   ? __expf(fmaxf(t1v + e0.y, 0.f)) : 1.f;
    float p2 = (mm8 & 4u)   ? __expf(fmaxf(t1v + e0.z, 0.f)) : 1.f;
    float p3 = (mm8 & 8u)   ? __expf(fmaxf(t1v + e0.w, 0.f)) : 1.f;
    float p4 = (mm8 & 16u)  ? __expf(fmaxf(t1v + e1.x, 0.f)) : 1.f;
    float p5 = (mm8 & 32u)  ? __expf(fmaxf(t1v + e1.y, 0.f)) : 1.f;
    float p6 = (mm8 & 64u)  ? __expf(fmaxf(t1v + e1.z, 0.f)) : 1.f;
    float p7 = (mm8 & 128u) ? __expf(fmaxf(t1v + e1.w, 0.f)) : 1.f;
    den += ((p0 + p1) + (p2 + p3)) + ((p4 + p5) + (p6 + p7));

    union { bf16x8 v; unsigned u[4]; } Af;
    Af.u[0] = f2bf_pk(p0, p1); Af.u[1] = f2bf_pk(p2, p3);
    Af.u[2] = f2bf_pk(p4, p5); Af.u[3] = f2bf_pk(p6, p7);

    acc[0] = __builtin_amdgcn_mfma_f32_16x16x32_bf16(Af.v, B0, acc[0], 0, 0, 0);
    acc[1] = __builtin_amdgcn_mfma_f32_16x16x32_bf16(Af.v, B1, acc[1], 0, 0, 0);
    acc[2] = __builtin_amdgcn_mfma_f32_16x16x32_bf16(Af.v, B2, acc[2], 0, 0, 0);
    acc[3] = __builtin_amdgcn_mfma_f32_16x16x32_bf16(Af.v, B3, acc[3], 0, 0, 0);

    mcur = mnext;
  }

  // den: quads own disjoint j subsets -> reduce over quads in-wave
  den += __shfl_xor(den, 16, 64);
  den += __shfl_xor(den, 32, 64);
  if (quad == 0) denos[w][m] = den;

  // per-wave partial C(16x64) into LDS
#pragma unroll
  for (int g = 0; g < 4; ++g)
#pragma unroll
    for (int r = 0; r < 4; ++r)
      os[w][quad * 4 + r][g * 16 + m] = acc[g][r];
  __syncthreads();

  // block reduce over the 4 waves + normalize + root-select + store
  {
    const int i = t >> 4, k4 = t & 15;
    float4 a = make_float4(0.f, 0.f, 0.f, 0.f);
    float d = 0.f;
#pragma unroll
    for (int ww = 0; ww < 4; ++ww) {
      float4 p = *reinterpret_cast<const float4*>(&os[ww][i][k4 * 4]);
      a.x += p.x; a.y += p.y; a.z += p.z; a.w += p.w;
      d += denos[ww][i];
    }
    const size_t row = (size_t)rowbase + i;
    float4 res;
    if (h_root[row] > 0.f) {
      const float inv = 1.f / d;
      res.x = a.x * inv; res.y = a.y * inv; res.z = a.z * inv; res.w = a.w * inv;
    } else {
      res = reinterpret_cast<const float4*>(h + row * DD)[k4];
    }
    reinterpret_cast<float4*>(out + row * DD)[k4] = res;
  }
}

extern "C" void kernel_launch(void* const* d_in, const int* in_sizes, int n_in,
                              void* d_out, int out_size, void* d_ws, size_t ws_size,
                              hipStream_t stream) {
  const float* h      = (const float*)d_in[0];
  const int*   adj    = (const int*)d_in[1];
  const float* h_root = (const float*)d_in[2];
  const float* W      = (const float*)d_in[3];
  const float* a1     = (const float*)d_in[4];
  const float* a2     = (const float*)d_in[5];
  float* out = (float*)d_out;

  // ws: hwT (bf16 frag-native, BN*DD) | t1 | t2 | masks (BN*64 u32)
  unsigned short* hwT = (unsigned short*)d_ws;
  float* t1 = (float*)(hwT + (size_t)BN * DD);
  float* t2 = t1 + BN;
  unsigned* masks = (unsigned*)(t2 + BN);

  kA<<<512 + BN / 4, 256, 0, stream>>>(h, W, a1, a2, adj, h_root, hwT, t1, t2, masks);
  k2_attn<<<BATCH * (NN / 16), 256, 0, stream>>>(hwT, masks, t1, t2, h, h_root, out);
}